// Round 5
// baseline (31589.771 us; speedup 1.0000x reference)
//
#include <hip/hip_runtime.h>

// ---------------------------------------------------------------------------
// GRU (B=64, T=512, d=512, H=1024) on MI355X gfx950.
// Reference semantics (Python precedence!): g = tanh(gx + (r ⊙ h) @ Wg_h).
// Two-phase step: phase1 computes r,z (h@Wr,z + x@Wx), writes rh = r⊙h hi/lo
// to global; device barrier; phase2 computes (rh)@Wg_h, gate fusion, h update;
// device barrier. hi/lo bf16 splitting of x, h, rh, Wh -> near-fp32 accuracy.
// 256 WGs (1/CU) x 4 waves; WG = 32 batch rows x 8 H-cols.
// Gate packing into 16-vcol B-fragments:
//   frag0 = [Whi_r(8) | Whi_z(8)]   -> C1 (phase 1)
//   frag1 = [Whi_g(8) | Wlo_g(8)]   -> C2 (x-part phase 1, rh-part phase 2)
//   frag2 = [Wlo_r(8) | Wlo_z(8)]   -> C3 (phase 1)
// Waves = K-quarters; cross-wave reduce via padded LDS; 256-thread
// elementwise (exactly 32x8 outputs). Flag barrier per phase (2/step).
// ---------------------------------------------------------------------------

#define DEV __device__ __forceinline__
typedef __attribute__((ext_vector_type(8))) short bf16x8;
typedef __attribute__((ext_vector_type(4))) float f32x4;

// ws layout (bytes)
constexpr size_t OFF_FLAGS = 0;             // 32 KB (A: 0..16K, B: 16K..32K)
constexpr size_t OFF_HBF   = 32768;         // 512 KB h bf16 [2 buf][hi/lo][64][1024]
constexpr size_t OFF_RH    = 589824;        // 256 KB rh bf16 [hi/lo][64][1024]
constexpr size_t OFF_WH    = 1ull << 20;    // 12 MB WhImg [128 slice][3][16][1024] pre-swizzled
constexpr size_t OFF_WX    = 16ull << 20;   // 4 MB  WxImg [128 slice][2][16][512]  pre-swizzled
constexpr size_t OFF_XHI   = 32ull << 20;   // 32 MB xhi [512 t][64 b][512 d]
constexpr size_t OFF_XLO   = 64ull << 20;   // 32 MB xlo

DEV short f2bf(float f) {
  union { float f; unsigned u; } v; v.f = f;
  unsigned r = v.u + 0x7FFFu + ((v.u >> 16) & 1u);   // RNE
  return (short)(r >> 16);
}
DEV float bf2f(short s) {
  union { unsigned u; float f; } v; v.u = ((unsigned)(unsigned short)s) << 16;
  return v.f;
}
DEV void gld_lds16(const void* g, void* l) {
  __builtin_amdgcn_global_load_lds((const __attribute__((address_space(1))) void*)g,
                                   (__attribute__((address_space(3))) void*)l, 16, 0, 0);
}
DEV f32x4 mfma(bf16x8 a, bf16x8 b, f32x4 c) {
  return __builtin_amdgcn_mfma_f32_16x16x32_bf16(a, b, c, 0, 0, 0);
}

// --------------------------- prep kernels ----------------------------------

// x [64][512][512] f32 -> xhi/xlo [512][64][512] bf16 (transposed for per-step rows)
__global__ void __launch_bounds__(256) k_prep_x(const float* __restrict__ x,
                                                short* __restrict__ xhi,
                                                short* __restrict__ xlo) {
  const int i = blockIdx.x * 256 + threadIdx.x;      // 2,097,152 threads
  const int d8 = i & 63;
  const int rest = i >> 6;
  const int b = rest & 63, t = rest >> 6;
  const float* src = x + ((size_t)(b * 512 + t)) * 512 + d8 * 8;
  bf16x8 hi, lo;
#pragma unroll
  for (int j = 0; j < 8; ++j) {
    float v = src[j];
    short h = f2bf(v);
    hi[j] = h;
    lo[j] = f2bf(v - bf2f(h));
  }
  const size_t o = ((size_t)(t * 64 + b)) * 512 + d8 * 8;
  *(bf16x8*)(xhi + o) = hi;
  *(bf16x8*)(xlo + o) = lo;
}

// Build pre-swizzled per-slice LDS images of Wh (hi+lo) and Wx (hi + lo-of-g).
__global__ void __launch_bounds__(256) k_prep_w(const float* __restrict__ Wr,
                                                const float* __restrict__ Wz,
                                                const float* __restrict__ Wg,
                                                char* __restrict__ WhImg,
                                                char* __restrict__ WxImg) {
  const int i = blockIdx.x * 256 + threadIdx.x;      // 1,048,576 threads
  const float* Wp[3] = {Wr, Wz, Wg};
  if (i < 786432) {                                  // h-part: 128*3*16*128
    const int k8 = i & 127;
    int rest = i >> 7;
    const int v = rest & 15; rest >>= 4;
    const int f = rest % 3;
    const int cs = rest / 3;
    int gate, isLo;
    if (f == 0)      { gate = (v < 8) ? 0 : 1; isLo = 0; }
    else if (f == 1) { gate = 2;               isLo = (v >= 8); }
    else             { gate = (v < 8) ? 0 : 1; isLo = 1; }
    const int colj = cs * 8 + (v & 7);
    const float* src = Wp[gate] + (size_t)(512 + k8 * 8) * 1024 + colj;
    bf16x8 o;
#pragma unroll
    for (int j = 0; j < 8; ++j) {
      float w = src[(size_t)j * 1024];
      short h = f2bf(w);
      o[j] = isLo ? f2bf(w - bf2f(h)) : h;
    }
    const size_t off = (size_t)cs * 98304 +
                       ((((f * 16 + v) * 1024 + k8 * 8) * 2) ^ ((v & 7) << 4));
    *(bf16x8*)(WhImg + off) = o;
  } else {                                           // x-part: 128*2*16*64
    const int c = i - 786432;
    const int k8 = c & 63;
    int rest = c >> 6;
    const int v = rest & 15; rest >>= 4;
    const int f = rest & 1;
    const int cs = rest >> 1;
    int gate, isLo;
    if (f == 0) { gate = (v < 8) ? 0 : 1; isLo = 0; }
    else        { gate = 2;               isLo = (v >= 8); }
    const int colj = cs * 8 + (v & 7);
    const float* src = Wp[gate] + (size_t)(k8 * 8) * 1024 + colj;
    bf16x8 o;
#pragma unroll
    for (int j = 0; j < 8; ++j) {
      float w = src[(size_t)j * 1024];
      short h = f2bf(w);
      o[j] = isLo ? f2bf(w - bf2f(h)) : h;
    }
    const size_t off = (size_t)cs * 32768 +
                       ((((f * 16 + v) * 512 + k8 * 8) * 2) ^ ((v & 7) << 4));
    *(bf16x8*)(WxImg + off) = o;
  }
}

// split h0 into buf0 hi/lo
__global__ void __launch_bounds__(256) k_prep_h(const float* __restrict__ h0,
                                                short* __restrict__ hbf) {
  const int i = blockIdx.x * 256 + threadIdx.x;      // 65536
  float h = h0[i];
  short hi = f2bf(h);
  hbf[i] = hi;
  hbf[65536 + i] = f2bf(h - bf2f(hi));
}

// --------------------------- persistent scan --------------------------------

__global__ void __launch_bounds__(256, 1) k_scan(
    const short* __restrict__ WhImg, const short* __restrict__ WxImg,
    const short* __restrict__ xhi, const short* __restrict__ xlo,
    const float* __restrict__ h0,
    const float* __restrict__ br, const float* __restrict__ bz,
    const float* __restrict__ bg,
    short* __restrict__ hbf, short* __restrict__ rhbuf,
    float* __restrict__ out, unsigned* __restrict__ flags) {
  __shared__ short WhL[49152];        // 96 KB (pre-swizzled)
  __shared__ short WxL[16384];        // 32 KB
  __shared__ float RED[4 * 2 * 560];  // 17.9 KB reduce buffer (padded)

  const int wg = blockIdx.x;          // 0..255
  const int bh = wg >> 7;             // batch half
  const int cs = wg & 127;            // 8-col slice
  const int tid = threadIdx.x;
  const int w = tid >> 6, l = tid & 63;
  const int lh = l & 15, lq = l >> 4;
  unsigned* flagsA = flags;
  unsigned* flagsB = flags + 4096;    // +16 KB

  // stage W images: linear copy (global pre-swizzled -> linear LDS)
  {
    const char* srcH = (const char*)WhImg + (size_t)cs * 98304;
    const char* srcX = (const char*)WxImg + (size_t)cs * 32768;
#pragma unroll
    for (int it = 0; it < 24; ++it)
      gld_lds16(srcH + it * 4096 + tid * 16, (char*)WhL + it * 4096 + w * 1024);
#pragma unroll
    for (int it = 0; it < 8; ++it)
      gld_lds16(srcX + it * 4096 + tid * 16, (char*)WxL + it * 4096 + w * 1024);
  }

  // elementwise identity: thread <-> (row32, col)
  const int row32 = tid >> 3, col = tid & 7;
  const int rowg = bh * 32 + row32;
  const int j = cs * 8 + col;
  float hold = h0[(size_t)rowg * 1024 + j];
  const float brv = br[j], bzv = bz[j], bgv = bg[j];

  // MFMA identity
  const int r0 = bh * 32 + lh;        // tile0 A-row (tile1: +16)
  const int sw = (lh & 7) << 4;
  const int bB0 = (0 * 16 + lh) * 2048;
  const int bB1 = (1 * 16 + lh) * 2048;
  const int bB2 = (2 * 16 + lh) * 2048;
  const int bX0 = (0 * 16 + lh) * 1024;
  const int bX1 = (1 * 16 + lh) * 1024;
  const int kq  = w * 256;            // this wave's h K-quarter
  const int kqx = w * 128;            // x K-quarter
  const int Tew = row32 >> 4, r16 = row32 & 15;   // elementwise reduce ids
  const float* R0 = RED + Tew * 560;
  __syncthreads();

  for (int t = 0; t < 512; ++t) {
    const int cur = t & 1;
    const short* hb = hbf + (size_t)cur * 131072;
    f32x4 C1[2] = {{0,0,0,0},{0,0,0,0}};
    f32x4 C3[2] = {{0,0,0,0},{0,0,0,0}};
    f32x4 C2[2] = {{0,0,0,0},{0,0,0,0}};   // g: x-part now, rh-part in phase 2
    // ---------------- phase 1: r,z pre-activations -------------------------
#pragma unroll
    for (int kk = 0; kk < 8; ++kk) {
      const int k = kq + kk * 32 + lq * 8;
      bf16x8 B1 = *(const bf16x8*)((const char*)WhL + ((bB0 + 2 * k) ^ sw));
      bf16x8 B3 = *(const bf16x8*)((const char*)WhL + ((bB2 + 2 * k) ^ sw));
#pragma unroll
      for (int T = 0; T < 2; ++T) {
        const size_t ro = (size_t)(r0 + T * 16) * 1024 + k;
        bf16x8 ahi = *(const bf16x8*)(hb + ro);
        bf16x8 alo = *(const bf16x8*)(hb + 65536 + ro);
        C1[T] = mfma(ahi, B1, C1[T]);
        C3[T] = mfma(ahi, B3, C3[T]);
        C1[T] = mfma(alo, B1, C1[T]);
      }
    }
#pragma unroll
    for (int kk = 0; kk < 4; ++kk) {
      const int k = kqx + kk * 32 + lq * 8;
      bf16x8 B1x = *(const bf16x8*)((const char*)WxL + ((bX0 + 2 * k) ^ sw));
      bf16x8 B2x = *(const bf16x8*)((const char*)WxL + ((bX1 + 2 * k) ^ sw));
#pragma unroll
      for (int T = 0; T < 2; ++T) {
        const size_t ro = ((size_t)t * 64 + r0 + T * 16) * 512 + k;
        bf16x8 xh = *(const bf16x8*)(xhi + ro);
        bf16x8 xl = *(const bf16x8*)(xlo + ro);
        C1[T] = mfma(xh, B1x, C1[T]);
        C1[T] = mfma(xl, B1x, C1[T]);
        C2[T] = mfma(xh, B2x, C2[T]);
        C2[T] = mfma(xl, B2x, C2[T]);
      }
    }
    // reduce r|z across waves
#pragma unroll
    for (int T = 0; T < 2; ++T) {
      float* RB = RED + (w * 2 + T) * 560;
#pragma unroll
      for (int i = 0; i < 4; ++i)
        RB[(lq * 4 + i) * 17 + lh] = C1[T][i] + C3[T][i];   // [16r][17] r|z
    }
    __syncthreads();
    float zz;
    {
      float rp = 0.f, zp = 0.f;
#pragma unroll
      for (int ww = 0; ww < 4; ++ww) {
        const float* R = R0 + ww * 1120;
        rp += R[r16 * 17 + col];
        zp += R[r16 * 17 + col + 8];
      }
      const float rr = 1.f / (1.f + __expf(-(rp + brv)));
      zz = 1.f / (1.f + __expf(-(zp + bzv)));
      const float rhv = rr * hold;                     // (r ⊙ h) -- exact split
      short hi = f2bf(rhv);
      rhbuf[(size_t)rowg * 1024 + j] = hi;
      rhbuf[65536 + (size_t)rowg * 1024 + j] = f2bf(rhv - bf2f(hi));
    }
    // ---------------- barrier A (rh exchange) ------------------------------
    __syncthreads();
    if (tid == 0) {
      __threadfence();
      __hip_atomic_store(&flagsA[wg * 16], (unsigned)(t + 1),
                         __ATOMIC_RELAXED, __HIP_MEMORY_SCOPE_AGENT);
    }
    if (w == 0) {
      const unsigned tgt = (unsigned)(t + 1);
#pragma unroll
      for (int i = 0; i < 4; ++i)
        while (__hip_atomic_load(&flagsA[(l * 4 + i) * 16], __ATOMIC_RELAXED,
                                 __HIP_MEMORY_SCOPE_AGENT) < tgt)
          __builtin_amdgcn_s_sleep(2);
      __threadfence();
    }
    __syncthreads();
    // ---------------- phase 2: g = (rh) @ Wg_h -----------------------------
#pragma unroll
    for (int kk = 0; kk < 8; ++kk) {
      const int k = kq + kk * 32 + lq * 8;
      bf16x8 B2 = *(const bf16x8*)((const char*)WhL + ((bB1 + 2 * k) ^ sw));
#pragma unroll
      for (int T = 0; T < 2; ++T) {
        const size_t ro = (size_t)(r0 + T * 16) * 1024 + k;
        bf16x8 rhi = *(const bf16x8*)(rhbuf + ro);
        bf16x8 rlo = *(const bf16x8*)(rhbuf + 65536 + ro);
        C2[T] = mfma(rhi, B2, C2[T]);
        C2[T] = mfma(rlo, B2, C2[T]);
      }
    }
    // reduce g (fold hi|lo column halves with shfl_xor 8)
#pragma unroll
    for (int T = 0; T < 2; ++T) {
      float* RB = RED + (w * 2 + T) * 560;
#pragma unroll
      for (int i = 0; i < 4; ++i) {
        float g2 = C2[T][i] + __shfl_xor(C2[T][i], 8);
        if (lh < 8) RB[272 + (lq * 4 + i) * 9 + lh] = g2;   // [16r][9]
      }
    }
    __syncthreads();
    {
      float gh = 0.f;
#pragma unroll
      for (int ww = 0; ww < 4; ++ww)
        gh += R0[ww * 1120 + 272 + r16 * 9 + col];
      const float e2 = __expf(2.f * (gh + bgv));
      const float gg = 1.f - 2.f / (e2 + 1.f);         // tanh
      hold = zz * hold + (1.f - zz) * gg;
      out[((size_t)rowg * 512 + t) * 1024 + j] = hold;
      short hi = f2bf(hold);
      short* hbn = hbf + (size_t)(cur ^ 1) * 131072;
      hbn[(size_t)rowg * 1024 + j] = hi;
      hbn[65536 + (size_t)rowg * 1024 + j] = f2bf(hold - bf2f(hi));
      if (t == 511) out[33554432 + (size_t)rowg * 1024 + j] = hold;
    }
    // ---------------- barrier B (h exchange) -------------------------------
    __syncthreads();
    if (tid == 0) {
      __threadfence();
      __hip_atomic_store(&flagsB[wg * 16], (unsigned)(t + 1),
                         __ATOMIC_RELAXED, __HIP_MEMORY_SCOPE_AGENT);
    }
    if (w == 0) {
      const unsigned tgt = (unsigned)(t + 1);
#pragma unroll
      for (int i = 0; i < 4; ++i)
        while (__hip_atomic_load(&flagsB[(l * 4 + i) * 16], __ATOMIC_RELAXED,
                                 __HIP_MEMORY_SCOPE_AGENT) < tgt)
          __builtin_amdgcn_s_sleep(2);
      __threadfence();
    }
    __syncthreads();
  }
}

// --------------------------- launch ----------------------------------------

extern "C" void kernel_launch(void* const* d_in, const int* in_sizes, int n_in,
                              void* d_out, int out_size, void* d_ws, size_t ws_size,
                              hipStream_t stream) {
  const float* x  = (const float*)d_in[0];
  const float* h0 = (const float*)d_in[1];
  const float* Wr = (const float*)d_in[2];
  const float* br = (const float*)d_in[3];
  const float* Wz = (const float*)d_in[4];
  const float* bz = (const float*)d_in[5];
  const float* Wg = (const float*)d_in[6];
  const float* bg = (const float*)d_in[7];
  float* out = (float*)d_out;
  char* ws = (char*)d_ws;

  unsigned* flags = (unsigned*)(ws + OFF_FLAGS);
  short* hbf = (short*)(ws + OFF_HBF);
  short* rhb = (short*)(ws + OFF_RH);
  char*  WhImg = ws + OFF_WH;
  char*  WxImg = ws + OFF_WX;
  short* xhi = (short*)(ws + OFF_XHI);
  short* xlo = (short*)(ws + OFF_XLO);

  hipMemsetAsync(flags, 0, 32768, stream);
  hipLaunchKernelGGL(k_prep_x, dim3(8192), dim3(256), 0, stream, x, xhi, xlo);
  hipLaunchKernelGGL(k_prep_w, dim3(4096), dim3(256), 0, stream, Wr, Wz, Wg, WhImg, WxImg);
  hipLaunchKernelGGL(k_prep_h, dim3(256), dim3(256), 0, stream, h0, hbf);
  hipLaunchKernelGGL(k_scan, dim3(256), dim3(256), 0, stream,
                     (const short*)WhImg, (const short*)WxImg, xhi, xlo,
                     h0, br, bz, bg, hbf, rhb, out, flags);
}

// Round 8
// 9642.934 us; speedup vs baseline: 3.2759x; 3.2759x over previous
//
#include <hip/hip_runtime.h>

// ---------------------------------------------------------------------------
// GRU (B=64, T=512, d=512, H=1024) on MI355X gfx950.
// g = tanh(gx + (r ⊙ h) @ Wg_h)  (Python precedence).
// Two-phase persistent scan, 256 WGs (1/CU) x 4 waves.
// Round 6/7/8: coherence via LLC (agent-scope relaxed atomics, sc1), NO fences.
//   - h, rh exchanged with __hip_atomic_load/store (bypass non-coherent L2s)
//   - flag barrier fence-free (vmcnt drain at s_barrier orders sc1 stores)
//   - rh-lo dropped (error budget ok), x-part MFMAs pipelined over barrier B
//   - elementwise: 128 threads x (32 rows x 4 col-pairs) -> 4B packed stores
// ---------------------------------------------------------------------------

#define DEV __device__ __forceinline__
typedef __attribute__((ext_vector_type(8))) short bf16x8;
typedef __attribute__((ext_vector_type(4))) float f32x4;

// ws layout (bytes)
constexpr size_t OFF_FLAGS = 0;             // 32 KB (A: 0..16K, B: 16K..32K)
constexpr size_t OFF_HBF   = 32768;         // 512 KB h bf16 [2 buf][hi/lo][64][1024]
constexpr size_t OFF_RH    = 589824;        // 128 KB rh bf16 [64][1024] (hi only)
constexpr size_t OFF_WH    = 1ull << 20;    // 12 MB WhImg [128 slice][3][16][1024] pre-swizzled
constexpr size_t OFF_WX    = 16ull << 20;   // 4 MB  WxImg [128 slice][2][16][512]  pre-swizzled
constexpr size_t OFF_XHI   = 32ull << 20;   // 32 MB xhi [512 t][64 b][512 d]
constexpr size_t OFF_XLO   = 64ull << 20;   // 32 MB xlo

DEV short f2bf(float f) {
  union { float f; unsigned u; } v; v.f = f;
  unsigned r = v.u + 0x7FFFu + ((v.u >> 16) & 1u);   // RNE
  return (short)(r >> 16);
}
DEV float bf2f(short s) {
  union { unsigned u; float f; } v; v.u = ((unsigned)(unsigned short)s) << 16;
  return v.f;
}
DEV unsigned pack2(float a, float b) {     // shorts at [j],[j+1] -> LE uint
  return ((unsigned)(unsigned short)f2bf(b) << 16) | (unsigned)(unsigned short)f2bf(a);
}
DEV void gld_lds16(const void* g, void* l) {
  __builtin_amdgcn_global_load_lds((const __attribute__((address_space(1))) void*)g,
                                   (__attribute__((address_space(3))) void*)l, 16, 0, 0);
}
DEV f32x4 mfma(bf16x8 a, bf16x8 b, f32x4 c) {
  return __builtin_amdgcn_mfma_f32_16x16x32_bf16(a, b, c, 0, 0, 0);
}
// coherent 16B fragment load via 2x 8B agent-scope relaxed atomics (sc1: LLC)
DEV bf16x8 ldg_sc16(const short* p) {
  union { unsigned long long q[2]; bf16x8 v; } u;
  u.q[0] = __hip_atomic_load((const unsigned long long*)p,
                             __ATOMIC_RELAXED, __HIP_MEMORY_SCOPE_AGENT);
  u.q[1] = __hip_atomic_load((const unsigned long long*)(p + 4),
                             __ATOMIC_RELAXED, __HIP_MEMORY_SCOPE_AGENT);
  return u.v;
}
DEV void stg_sc4(short* p, unsigned v) {    // coherent packed 2x bf16 store
  __hip_atomic_store((unsigned*)p, v, __ATOMIC_RELAXED, __HIP_MEMORY_SCOPE_AGENT);
}

// --------------------------- prep kernels ----------------------------------

__global__ void __launch_bounds__(256) k_prep_x(const float* __restrict__ x,
                                                short* __restrict__ xhi,
                                                short* __restrict__ xlo) {
  const int i = blockIdx.x * 256 + threadIdx.x;      // 2,097,152 threads
  const int d8 = i & 63;
  const int rest = i >> 6;
  const int b = rest & 63, t = rest >> 6;
  const float* src = x + ((size_t)(b * 512 + t)) * 512 + d8 * 8;
  bf16x8 hi, lo;
#pragma unroll
  for (int j = 0; j < 8; ++j) {
    float v = src[j];
    short h = f2bf(v);
    hi[j] = h;
    lo[j] = f2bf(v - bf2f(h));
  }
  const size_t o = ((size_t)(t * 64 + b)) * 512 + d8 * 8;
  *(bf16x8*)(xhi + o) = hi;
  *(bf16x8*)(xlo + o) = lo;
}

__global__ void __launch_bounds__(256) k_prep_w(const float* __restrict__ Wr,
                                                const float* __restrict__ Wz,
                                                const float* __restrict__ Wg,
                                                char* __restrict__ WhImg,
                                                char* __restrict__ WxImg) {
  const int i = blockIdx.x * 256 + threadIdx.x;      // 1,048,576 threads
  const float* Wp[3] = {Wr, Wz, Wg};
  if (i < 786432) {                                  // h-part: 128*3*16*128
    const int k8 = i & 127;
    int rest = i >> 7;
    const int v = rest & 15; rest >>= 4;
    const int f = rest % 3;
    const int cs = rest / 3;
    int gate, isLo;
    if (f == 0)      { gate = (v < 8) ? 0 : 1; isLo = 0; }
    else if (f == 1) { gate = 2;               isLo = (v >= 8); }
    else             { gate = (v < 8) ? 0 : 1; isLo = 1; }
    const int colj = cs * 8 + (v & 7);
    const float* src = Wp[gate] + (size_t)(512 + k8 * 8) * 1024 + colj;
    bf16x8 o;
#pragma unroll
    for (int j = 0; j < 8; ++j) {
      float w = src[(size_t)j * 1024];
      short h = f2bf(w);
      o[j] = isLo ? f2bf(w - bf2f(h)) : h;
    }
    const size_t off = (size_t)cs * 98304 +
                       ((((f * 16 + v) * 1024 + k8 * 8) * 2) ^ ((v & 7) << 4));
    *(bf16x8*)(WhImg + off) = o;
  } else {                                           // x-part: 128*2*16*64
    const int c = i - 786432;
    const int k8 = c & 63;
    int rest = c >> 6;
    const int v = rest & 15; rest >>= 4;
    const int f = rest & 1;
    const int cs = rest >> 1;
    int gate, isLo;
    if (f == 0) { gate = (v < 8) ? 0 : 1; isLo = 0; }
    else        { gate = 2;               isLo = (v >= 8); }
    const int colj = cs * 8 + (v & 7);
    const float* src = Wp[gate] + (size_t)(k8 * 8) * 1024 + colj;
    bf16x8 o;
#pragma unroll
    for (int j = 0; j < 8; ++j) {
      float w = src[(size_t)j * 1024];
      short h = f2bf(w);
      o[j] = isLo ? f2bf(w - bf2f(h)) : h;
    }
    const size_t off = (size_t)cs * 32768 +
                       ((((f * 16 + v) * 512 + k8 * 8) * 2) ^ ((v & 7) << 4));
    *(bf16x8*)(WxImg + off) = o;
  }
}

__global__ void __launch_bounds__(256) k_prep_h(const float* __restrict__ h0,
                                                short* __restrict__ hbf) {
  const int i = blockIdx.x * 256 + threadIdx.x;      // 65536
  float h = h0[i];
  short hi = f2bf(h);
  hbf[i] = hi;
  hbf[65536 + i] = f2bf(h - bf2f(hi));
}

// --------------------------- persistent scan --------------------------------

DEV void gbar(unsigned* flg, int wg, int w, int l, int tid, unsigned tgt) {
  __syncthreads();                        // drains vmcnt -> sc stores at LLC
  if (tid == 0)
    __hip_atomic_store(&flg[wg * 16], tgt, __ATOMIC_RELAXED,
                       __HIP_MEMORY_SCOPE_AGENT);
  if (w == 0) {
#pragma unroll
    for (int i = 0; i < 4; ++i)
      while (__hip_atomic_load(&flg[(l * 4 + i) * 16], __ATOMIC_RELAXED,
                               __HIP_MEMORY_SCOPE_AGENT) < tgt)
        __builtin_amdgcn_s_sleep(2);
  }
  __syncthreads();
}

__global__ void __launch_bounds__(256, 1) k_scan(
    const short* __restrict__ WhImg, const short* __restrict__ WxImg,
    const short* __restrict__ xhi, const short* __restrict__ xlo,
    const float* __restrict__ h0,
    const float* __restrict__ br, const float* __restrict__ bz,
    const float* __restrict__ bg,
    short* __restrict__ hbf, short* __restrict__ rhbuf,
    float* __restrict__ out, unsigned* __restrict__ flags) {
  __shared__ short WhL[49152];        // 96 KB (pre-swizzled)
  __shared__ short WxL[16384];        // 32 KB
  __shared__ float RED[4 * 2 * 560];  // 17.9 KB reduce buffer (padded)

  const int wg = blockIdx.x;          // 0..255
  const int bh = wg >> 7;             // batch half
  const int cs = wg & 127;            // 8-col slice
  const int tid = threadIdx.x;
  const int w = tid >> 6, l = tid & 63;
  const int lh = l & 15, lq = l >> 4;
  unsigned* flagsA = flags;
  unsigned* flagsB = flags + 4096;    // +16 KB

  // stage W images (linear gld_lds copy; global is pre-swizzled)
  {
    const char* srcH = (const char*)WhImg + (size_t)cs * 98304;
    const char* srcX = (const char*)WxImg + (size_t)cs * 32768;
#pragma unroll
    for (int it = 0; it < 24; ++it)
      gld_lds16(srcH + it * 4096 + tid * 16, (char*)WhL + it * 4096 + w * 1024);
#pragma unroll
    for (int it = 0; it < 8; ++it)
      gld_lds16(srcX + it * 4096 + tid * 16, (char*)WxL + it * 4096 + w * 1024);
  }

  // elementwise identity: 128 threads x (32 rows x 4 col-pairs), 2 cols each
  const int row32 = tid >> 2, cp = tid & 3;          // valid for tid<128
  const int rowg = bh * 32 + row32;
  const int j0 = cs * 8 + cp * 2;
  float2 hold = {0.f, 0.f};
  float2 brv = {0.f, 0.f}, bzv = {0.f, 0.f}, bgv = {0.f, 0.f};
  if (tid < 128) {
    hold = *(const float2*)&h0[(size_t)rowg * 1024 + j0];
    brv = *(const float2*)&br[j0];
    bzv = *(const float2*)&bz[j0];
    bgv = *(const float2*)&bg[j0];
  }

  // MFMA identity
  const int r0 = bh * 32 + lh;        // tile0 A-row (tile1: +16)
  const int sw = (lh & 7) << 4;
  const int bB0 = (0 * 16 + lh) * 2048;
  const int bB1 = (1 * 16 + lh) * 2048;
  const int bB2 = (2 * 16 + lh) * 2048;
  const int bX0 = (0 * 16 + lh) * 1024;
  const int bX1 = (1 * 16 + lh) * 1024;
  const int kq  = w * 256;            // this wave's h K-quarter
  const int kqx = w * 128;            // x K-quarter
  const int Tew = row32 >> 4, r16 = row32 & 15;
  const float* R0 = RED + Tew * 560;

  f32x4 C1[2], C2[2];
  // x-part of step tt -> fresh C1 (r|z) and C2 (g); h-independent
  auto xpart = [&](int tt) {
#pragma unroll
    for (int T = 0; T < 2; ++T) { C1[T] = (f32x4){0,0,0,0}; C2[T] = (f32x4){0,0,0,0}; }
#pragma unroll
    for (int kk = 0; kk < 4; ++kk) {
      const int k = kqx + kk * 32 + lq * 8;
      bf16x8 B1x = *(const bf16x8*)((const char*)WxL + ((bX0 + 2 * k) ^ sw));
      bf16x8 B2x = *(const bf16x8*)((const char*)WxL + ((bX1 + 2 * k) ^ sw));
#pragma unroll
      for (int T = 0; T < 2; ++T) {
        const size_t ro = ((size_t)tt * 64 + r0 + T * 16) * 512 + k;
        bf16x8 xh = *(const bf16x8*)(xhi + ro);
        bf16x8 xl = *(const bf16x8*)(xlo + ro);
        C1[T] = mfma(xh, B1x, C1[T]);
        C1[T] = mfma(xl, B1x, C1[T]);
        C2[T] = mfma(xh, B2x, C2[T]);
        C2[T] = mfma(xl, B2x, C2[T]);
      }
    }
  };

  __syncthreads();                    // W staging complete
  xpart(0);

  for (int t = 0; t < 512; ++t) {
    const int cur = t & 1;
    const short* hb = hbf + (size_t)cur * 131072;
    float zz0 = 0.f, zz1 = 0.f;
    // ---------------- phase 1: r,z ----------------------------------------
    bf16x8 AH[8][2], AL[8][2];        // issue all coherent h loads up front
#pragma unroll
    for (int kk = 0; kk < 8; ++kk) {
      const int k = kq + kk * 32 + lq * 8;
#pragma unroll
      for (int T = 0; T < 2; ++T) {
        const size_t ro = (size_t)(r0 + T * 16) * 1024 + k;
        AH[kk][T] = ldg_sc16(hb + ro);
        AL[kk][T] = ldg_sc16(hb + 65536 + ro);
      }
    }
    f32x4 C3[2] = {{0,0,0,0},{0,0,0,0}};
#pragma unroll
    for (int kk = 0; kk < 8; ++kk) {
      const int k = kq + kk * 32 + lq * 8;
      bf16x8 B1 = *(const bf16x8*)((const char*)WhL + ((bB0 + 2 * k) ^ sw));
      bf16x8 B3 = *(const bf16x8*)((const char*)WhL + ((bB2 + 2 * k) ^ sw));
#pragma unroll
      for (int T = 0; T < 2; ++T) {
        C1[T] = mfma(AH[kk][T], B1, C1[T]);
        C3[T] = mfma(AH[kk][T], B3, C3[T]);
        C1[T] = mfma(AL[kk][T], B1, C1[T]);
      }
    }
#pragma unroll
    for (int T = 0; T < 2; ++T) {
      float* RB = RED + (w * 2 + T) * 560;
#pragma unroll
      for (int i = 0; i < 4; ++i)
        RB[(lq * 4 + i) * 17 + lh] = C1[T][i] + C3[T][i];   // [16r][17] r|z
    }
    __syncthreads();
    if (tid < 128) {
      float rp0 = 0.f, rp1 = 0.f, zp0 = 0.f, zp1 = 0.f;
      const int c0 = cp * 2;
#pragma unroll
      for (int ww = 0; ww < 4; ++ww) {
        const float* R = R0 + ww * 1120;
        rp0 += R[r16 * 17 + c0];     rp1 += R[r16 * 17 + c0 + 1];
        zp0 += R[r16 * 17 + c0 + 8]; zp1 += R[r16 * 17 + c0 + 9];
      }
      const float rr0 = 1.f / (1.f + __expf(-(rp0 + brv.x)));
      const float rr1 = 1.f / (1.f + __expf(-(rp1 + brv.y)));
      zz0 = 1.f / (1.f + __expf(-(zp0 + bzv.x)));
      zz1 = 1.f / (1.f + __expf(-(zp1 + bzv.y)));
      stg_sc4(&rhbuf[(size_t)rowg * 1024 + j0], pack2(rr0 * hold.x, rr1 * hold.y));
    }
    gbar(flagsA, wg, w, l, tid, (unsigned)(t + 1));
    // ---------------- phase 2: g = (rh) @ Wg_h -----------------------------
    bf16x8 RH[8][2];
#pragma unroll
    for (int kk = 0; kk < 8; ++kk) {
      const int k = kq + kk * 32 + lq * 8;
#pragma unroll
      for (int T = 0; T < 2; ++T)
        RH[kk][T] = ldg_sc16(rhbuf + (size_t)(r0 + T * 16) * 1024 + k);
    }
#pragma unroll
    for (int kk = 0; kk < 8; ++kk) {
      const int k = kq + kk * 32 + lq * 8;
      bf16x8 B2 = *(const bf16x8*)((const char*)WhL + ((bB1 + 2 * k) ^ sw));
#pragma unroll
      for (int T = 0; T < 2; ++T)
        C2[T] = mfma(RH[kk][T], B2, C2[T]);
    }
#pragma unroll
    for (int T = 0; T < 2; ++T) {
      float* RB = RED + (w * 2 + T) * 560;
#pragma unroll
      for (int i = 0; i < 4; ++i) {
        float g2 = C2[T][i] + __shfl_xor(C2[T][i], 8);      // hi+lo col fold
        if (lh < 8) RB[272 + (lq * 4 + i) * 9 + lh] = g2;   // [16r][9]
      }
    }
    __syncthreads();
    if (tid < 128) {
      float gh0 = 0.f, gh1 = 0.f;
      const int c0 = cp * 2;
#pragma unroll
      for (int ww = 0; ww < 4; ++ww) {
        gh0 += R0[ww * 1120 + 272 + r16 * 9 + c0];
        gh1 += R0[ww * 1120 + 272 + r16 * 9 + c0 + 1];
      }
      const float e0 = __expf(2.f * (gh0 + bgv.x));
      const float e1 = __expf(2.f * (gh1 + bgv.y));
      const float gg0 = 1.f - 2.f / (e0 + 1.f);
      const float gg1 = 1.f - 2.f / (e1 + 1.f);
      hold.x = zz0 * hold.x + (1.f - zz0) * gg0;
      hold.y = zz1 * hold.y + (1.f - zz1) * gg1;
      *(float2*)(out + ((size_t)rowg * 512 + t) * 1024 + j0) = hold;
      short* hbn = hbf + (size_t)(cur ^ 1) * 131072;
      const short h0s = f2bf(hold.x), h1s = f2bf(hold.y);
      stg_sc4(&hbn[(size_t)rowg * 1024 + j0],
              ((unsigned)(unsigned short)h1s << 16) | (unsigned)(unsigned short)h0s);
      stg_sc4(&hbn[65536 + (size_t)rowg * 1024 + j0],
              pack2(hold.x - bf2f(h0s), hold.y - bf2f(h1s)));
      if (t == 511)
        *(float2*)(out + 33554432 + (size_t)rowg * 1024 + j0) = hold;
    }
    if (t < 511) xpart(t + 1);        // h-independent: hides barrier-B latency
    gbar(flagsB, wg, w, l, tid, (unsigned)(t + 1));
  }
}

// --------------------------- launch ----------------------------------------

extern "C" void kernel_launch(void* const* d_in, const int* in_sizes, int n_in,
                              void* d_out, int out_size, void* d_ws, size_t ws_size,
                              hipStream_t stream) {
  const float* x  = (const float*)d_in[0];
  const float* h0 = (const float*)d_in[1];
  const float* Wr = (const float*)d_in[2];
  const float* br = (const float*)d_in[3];
  const float* Wz = (const float*)d_in[4];
  const float* bz = (const float*)d_in[5];
  const float* Wg = (const float*)d_in[6];
  const float* bg = (const float*)d_in[7];
  float* out = (float*)d_out;
  char* ws = (char*)d_ws;

  unsigned* flags = (unsigned*)(ws + OFF_FLAGS);
  short* hbf = (short*)(ws + OFF_HBF);
  short* rhb = (short*)(ws + OFF_RH);
  char*  WhImg = ws + OFF_WH;
  char*  WxImg = ws + OFF_WX;
  short* xhi = (short*)(ws + OFF_XHI);
  short* xlo = (short*)(ws + OFF_XLO);

  hipMemsetAsync(flags, 0, 32768, stream);
  hipLaunchKernelGGL(k_prep_x, dim3(8192), dim3(256), 0, stream, x, xhi, xlo);
  hipLaunchKernelGGL(k_prep_w, dim3(4096), dim3(256), 0, stream, Wr, Wz, Wg, WhImg, WxImg);
  hipLaunchKernelGGL(k_prep_h, dim3(256), dim3(256), 0, stream, h0, hbf);
  hipLaunchKernelGGL(k_scan, dim3(256), dim3(256), 0, stream,
                     (const short*)WhImg, (const short*)WxImg, xhi, xlo,
                     h0, br, bz, bg, hbf, rhb, out, flags);
}